// Round 2
// 657.600 us; speedup vs baseline: 1.1183x; 1.1183x over previous
//
#include <hip/hip_runtime.h>

typedef unsigned short u16;
typedef unsigned int u32;
typedef _Float16 f16;
typedef __attribute__((ext_vector_type(8))) _Float16 half8;
typedef __attribute__((ext_vector_type(4))) float floatx4;

#define HWSZ 40000
#define NB 40

__device__ __forceinline__ u16 f2h(float f) {
  union { f16 h; u16 u; } c; c.h = (f16)f; return c.u;
}

// ---------------- K0: weight fp32 -> fp16 cast + rel table ----------------
__global__ __launch_bounds__(256) void k_tw(
    const float* __restrict__ Wmap, const float* __restrict__ Wq,
    const float* __restrict__ Wk, const float* __restrict__ Wv,
    const float* __restrict__ relh, const float* __restrict__ relw,
    u16* __restrict__ wmapB, u16* __restrict__ wqB,
    u16* __restrict__ wkB, u16* __restrict__ wvB, u16* __restrict__ relB) {
  int which = blockIdx.y;
  int idx = blockIdx.x * 256 + threadIdx.x;
  if (which == 4) {
    if (idx < 8192) {
      int j = idx >> 6, d = idx & 63;
      float val = 0.f;
      if (j < 121) {
        int ky = j / 11, kx = j - ky * 11;
        val = (d < 32) ? relh[ky * 32 + d] : relw[kx * 32 + (d - 32)];
      }
      relB[idx] = f2h(val);
    }
    return;
  }
  const float* src; u16* dst; int n;
  if (which == 0)      { src = Wmap; dst = wmapB; n = 131072; }
  else if (which == 1) { src = Wq;   dst = wqB;   n = 65536; }
  else if (which == 2) { src = Wk;   dst = wkB;   n = 65536; }
  else                 { src = Wv;   dst = wvB;   n = 65536; }
  if (idx < n) dst[idx] = f2h(src[idx]);
}

// ---------------- K1a: n_aux = relu(W_map @ [noisy;aux] + b), f16 MFMA ----------------
// output fp16 pixel-major [b][hw][256]  (byte-identical to the 735us passing version)
__global__ __launch_bounds__(256) void k_naux(
    const float* __restrict__ noisy, const float* __restrict__ aux,
    const u16* __restrict__ wmapB, const float* __restrict__ bmap,
    u16* __restrict__ naux) {
  __shared__ __align__(16) u16 xs[32 * 520];
  __shared__ __align__(16) u16 os[32 * 264];
  int t = threadIdx.x;
  int bi = blockIdx.y;
  int hw0 = blockIdx.x * 32;
  int wave = t >> 6, lane = t & 63;
  int quad = lane >> 4, l16 = lane & 15;

#pragma unroll
  for (int m = 0; m < 16; ++m) {
    int idx = m * 256 + t;
    int ci = idx >> 3, sub = idx & 7;
    const float* src = (ci < 256 ? noisy + (size_t)(bi * 256 + ci) * HWSZ
                                 : aux + (size_t)(bi * 256 + (ci - 256)) * HWSZ) + hw0 + sub * 4;
    float4 vx = *(const float4*)src;
    xs[(sub * 4 + 0) * 520 + ci] = f2h(vx.x);
    xs[(sub * 4 + 1) * 520 + ci] = f2h(vx.y);
    xs[(sub * 4 + 2) * 520 + ci] = f2h(vx.z);
    xs[(sub * 4 + 3) * 520 + ci] = f2h(vx.w);
  }
  __syncthreads();

  floatx4 acc[4][2];
#pragma unroll
  for (int mt = 0; mt < 4; ++mt)
#pragma unroll
    for (int nt = 0; nt < 2; ++nt) acc[mt][nt] = (floatx4){0.f, 0.f, 0.f, 0.f};

  const u16* wbase = wmapB + (size_t)(wave * 64 + l16) * 512 + quad * 8;
#pragma unroll 4
  for (int ks = 0; ks < 16; ++ks) {
    half8 a[4], b[2];
#pragma unroll
    for (int mt = 0; mt < 4; ++mt)
      a[mt] = *(const half8*)(wbase + mt * 16 * 512 + ks * 32);
#pragma unroll
    for (int nt = 0; nt < 2; ++nt)
      b[nt] = *(const half8*)(&xs[(nt * 16 + l16) * 520 + ks * 32 + quad * 8]);
#pragma unroll
    for (int mt = 0; mt < 4; ++mt)
#pragma unroll
      for (int nt = 0; nt < 2; ++nt)
        acc[mt][nt] = __builtin_amdgcn_mfma_f32_16x16x32_f16(a[mt], b[nt], acc[mt][nt], 0, 0, 0);
  }

#pragma unroll
  for (int mt = 0; mt < 4; ++mt) {
#pragma unroll
    for (int r = 0; r < 4; ++r) {
      int co = wave * 64 + mt * 16 + quad * 4 + r;
      float bv = bmap[co];
#pragma unroll
      for (int nt = 0; nt < 2; ++nt) {
        int px = nt * 16 + l16;
        os[px * 264 + co] = f2h(fmaxf(acc[mt][nt][r] + bv, 0.f));
      }
    }
  }
  __syncthreads();

#pragma unroll
  for (int m = 0; m < 4; ++m) {
    int idx = m * 256 + t;
    int px = idx >> 5, sub = idx & 31;
    *(uint4*)(naux + ((size_t)bi * HWSZ + hw0 + px) * 256 + sub * 8) =
        *(const uint4*)(&os[px * 264 + sub * 8]);
  }
}

// ---------------- K1b: q,k from naux; v from noisy — f16 MFMA ----------------
// outputs fp16 pixel-major [b][hw][256]  (byte-identical to the 735us passing version)
__global__ __launch_bounds__(256) void k_qkv(
    const u16* __restrict__ naux, const float* __restrict__ noisy,
    const u16* __restrict__ wqB, const u16* __restrict__ wkB,
    const u16* __restrict__ wvB,
    u16* __restrict__ q, u16* __restrict__ k, u16* __restrict__ v) {
  __shared__ __align__(16) u16 xs[32 * 264];
  __shared__ __align__(16) u16 os[32 * 264];
  int t = threadIdx.x;
  int bi = blockIdx.y;
  int hw0 = blockIdx.x * 32;
  int wave = t >> 6, lane = t & 63;
  int quad = lane >> 4, l16 = lane & 15;

#pragma unroll
  for (int m = 0; m < 4; ++m) {
    int idx = m * 256 + t;
    int px = idx >> 5, sub = idx & 31;
    *(uint4*)(&xs[px * 264 + sub * 8]) =
        *(const uint4*)(naux + ((size_t)bi * HWSZ + hw0 + px) * 256 + sub * 8);
  }
  __syncthreads();

#pragma unroll 1
  for (int pass = 0; pass < 2; ++pass) {
    const u16* wb = (pass == 0 ? wqB : wkB) + (size_t)(wave * 64 + l16) * 256 + quad * 8;
    floatx4 acc[4][2];
#pragma unroll
    for (int mt = 0; mt < 4; ++mt)
#pragma unroll
      for (int nt = 0; nt < 2; ++nt) acc[mt][nt] = (floatx4){0.f, 0.f, 0.f, 0.f};
#pragma unroll 4
    for (int ks = 0; ks < 8; ++ks) {
      half8 a[4], b[2];
#pragma unroll
      for (int mt = 0; mt < 4; ++mt)
        a[mt] = *(const half8*)(wb + mt * 16 * 256 + ks * 32);
#pragma unroll
      for (int nt = 0; nt < 2; ++nt)
        b[nt] = *(const half8*)(&xs[(nt * 16 + l16) * 264 + ks * 32 + quad * 8]);
#pragma unroll
      for (int mt = 0; mt < 4; ++mt)
#pragma unroll
        for (int nt = 0; nt < 2; ++nt)
          acc[mt][nt] = __builtin_amdgcn_mfma_f32_16x16x32_f16(a[mt], b[nt], acc[mt][nt], 0, 0, 0);
    }
    float scale = pass == 0 ? 0.125f : 1.f;
#pragma unroll
    for (int mt = 0; mt < 4; ++mt)
#pragma unroll
      for (int r = 0; r < 4; ++r) {
        int co = wave * 64 + mt * 16 + quad * 4 + r;
#pragma unroll
        for (int nt = 0; nt < 2; ++nt)
          os[(nt * 16 + l16) * 264 + co] = f2h(acc[mt][nt][r] * scale);
      }
    __syncthreads();
    u16* dst = pass == 0 ? q : k;
#pragma unroll
    for (int m = 0; m < 4; ++m) {
      int idx = m * 256 + t;
      int px = idx >> 5, sub = idx & 31;
      *(uint4*)(dst + ((size_t)bi * HWSZ + hw0 + px) * 256 + sub * 8) =
          *(const uint4*)(&os[px * 264 + sub * 8]);
    }
    __syncthreads();
  }

#pragma unroll
  for (int m = 0; m < 8; ++m) {
    int idx = m * 256 + t;
    int ci = idx >> 3, sub = idx & 7;
    const float* src = noisy + (size_t)(bi * 256 + ci) * HWSZ + hw0 + sub * 4;
    float4 vx = *(const float4*)src;
    xs[(sub * 4 + 0) * 264 + ci] = f2h(vx.x);
    xs[(sub * 4 + 1) * 264 + ci] = f2h(vx.y);
    xs[(sub * 4 + 2) * 264 + ci] = f2h(vx.z);
    xs[(sub * 4 + 3) * 264 + ci] = f2h(vx.w);
  }
  __syncthreads();
  {
    const u16* wb = wvB + (size_t)(wave * 64 + l16) * 256 + quad * 8;
    floatx4 acc[4][2];
#pragma unroll
    for (int mt = 0; mt < 4; ++mt)
#pragma unroll
      for (int nt = 0; nt < 2; ++nt) acc[mt][nt] = (floatx4){0.f, 0.f, 0.f, 0.f};
#pragma unroll 4
    for (int ks = 0; ks < 8; ++ks) {
      half8 a[4], b[2];
#pragma unroll
      for (int mt = 0; mt < 4; ++mt)
        a[mt] = *(const half8*)(wb + mt * 16 * 256 + ks * 32);
#pragma unroll
      for (int nt = 0; nt < 2; ++nt)
        b[nt] = *(const half8*)(&xs[(nt * 16 + l16) * 264 + ks * 32 + quad * 8]);
#pragma unroll
      for (int mt = 0; mt < 4; ++mt)
#pragma unroll
        for (int nt = 0; nt < 2; ++nt)
          acc[mt][nt] = __builtin_amdgcn_mfma_f32_16x16x32_f16(a[mt], b[nt], acc[mt][nt], 0, 0, 0);
    }
#pragma unroll
    for (int mt = 0; mt < 4; ++mt)
#pragma unroll
      for (int r = 0; r < 4; ++r) {
        int co = wave * 64 + mt * 16 + quad * 4 + r;
#pragma unroll
        for (int nt = 0; nt < 2; ++nt)
          os[(nt * 16 + l16) * 264 + co] = f2h(acc[mt][nt][r]);
      }
    __syncthreads();
#pragma unroll
    for (int m = 0; m < 4; ++m) {
      int idx = m * 256 + t;
      int px = idx >> 5, sub = idx & 31;
      *(uint4*)(v + ((size_t)bi * HWSZ + hw0 + px) * 256 + sub * 8) =
          *(const uint4*)(&os[px * 264 + sub * 8]);
    }
  }
}

// ---------------- K2: halo block attention — f16 MFMA, 1 wave per (b,block,head) ----------------
// Output fp16 pixel-major into o16 (coalesced 32B segments); XCD-chunked block swizzle.
__global__ __launch_bounds__(64) void k_attn(
    const u16* __restrict__ q, const u16* __restrict__ k,
    const u16* __restrict__ v, const u16* __restrict__ relB,
    u16* __restrict__ o16) {
  __shared__ __align__(16) u16 vt[16 * 512];   // V^T frags (16 KB)
  __shared__ __align__(16) u16 pf[8 * 512];    // P frags   (8 KB)

  int t = threadIdx.x;           // single wave
  int bb = blockIdx.z;
  int head = blockIdx.y;
  // XCD-aware swizzle: 1600 % 8 == 0 -> bijective chunked remap.
  int bid = blockIdx.x;
  int sb = (bid & 7) * 200 + (bid >> 3);
  int by = sb / NB, bx = sb % NB;
  int l16 = t & 15, quad = t >> 4;
  int hi = l16 >> 3, lowl = l16 & 7;

  const size_t hbase = (size_t)bb * HWSZ;
  const int hoff = head * 64;

  // ---- stage V^T into vt (frag-swizzled) ----
#pragma unroll 4
  for (int it = 0; it < 16; ++it) {
    int idx = it * 64 + t;       // 0..1023
    int j = idx >> 3, c8 = idx & 7;
    int jc = min(j, 120);
    int ky = jc / 11, kx = jc - ky * 11;
    int y = by * 5 - 3 + ky, x = bx * 5 - 3 + kx;
    bool inb = (j <= 120) && (y >= 0) && (y < 200) && (x >= 0) && (x < 200);
    int yc = min(max(y, 0), 199), xc = min(max(x, 0), 199);
    uint4 raw = *(const uint4*)(v + (hbase + yc * 200 + xc) * 256 + hoff + c8 * 8);
    if (!inb) raw = (uint4){0, 0, 0, 0};
    u32 w[4] = {raw.x, raw.y, raw.z, raw.w};
    int base16 = ((c8 >> 1) * 4 + (j >> 5)) * 512 + ((((j >> 3) & 3) * 16 + (c8 & 1) * 8) * 8) + (j & 7);
#pragma unroll
    for (int i = 0; i < 8; ++i) {
      u16 val = (u16)((i & 1) ? (w[i >> 1] >> 16) : (w[i >> 1] & 0xffffu));
      vt[base16 + i * 8] = val;
    }
  }

  // ---- Q a-frags from global ----
  half8 aq[2][2];
#pragma unroll
  for (int mt = 0; mt < 2; ++mt) {
    int i = min(mt * 16 + l16, 24);
    int y = by * 5 + i / 5, x = bx * 5 + i % 5;
    const u16* qb = q + (hbase + y * 200 + x) * 256 + hoff;
#pragma unroll
    for (int ks = 0; ks < 2; ++ks)
      aq[mt][ks] = *(const half8*)(qb + ks * 32 + quad * 8);
  }

  // ---- S = Q.K^T + Q.Rel^T ----
  floatx4 acc[2][8];
#pragma unroll
  for (int mt = 0; mt < 2; ++mt)
#pragma unroll
    for (int nt = 0; nt < 8; ++nt) acc[mt][nt] = (floatx4){0.f, 0.f, 0.f, 0.f};

#pragma unroll 2
  for (int nt = 0; nt < 8; ++nt) {
    int j = nt * 16 + l16;
    int jc = min(j, 120);
    int ky = jc / 11, kx = jc - ky * 11;
    int y = by * 5 - 3 + ky, x = bx * 5 - 3 + kx;
    bool inb = (y >= 0) && (y < 200) && (x >= 0) && (x < 200);
    int yc = min(max(y, 0), 199), xc = min(max(x, 0), 199);
    const u16* kb = k + (hbase + yc * 200 + xc) * 256 + hoff;
    const u16* rb = relB + jc * 64;
#pragma unroll
    for (int ks = 0; ks < 2; ++ks) {
      uint4 raw = *(const uint4*)(kb + ks * 32 + quad * 8);
      if (!inb) raw = (uint4){0, 0, 0, 0};
      union { uint4 u; half8 h; } kc; kc.u = raw;
      half8 rl = *(const half8*)(rb + ks * 32 + quad * 8);
#pragma unroll
      for (int mt = 0; mt < 2; ++mt) {
        acc[mt][nt] = __builtin_amdgcn_mfma_f32_16x16x32_f16(aq[mt][ks], kc.h, acc[mt][nt], 0, 0, 0);
        acc[mt][nt] = __builtin_amdgcn_mfma_f32_16x16x32_f16(aq[mt][ks], rl, acc[mt][nt], 0, 0, 0);
      }
    }
  }
  __syncthreads();  // vt staged

  // ---- softmax in registers + write P frags ----
  float rinv[2][4];
#pragma unroll
  for (int mt = 0; mt < 2; ++mt) {
#pragma unroll
    for (int r = 0; r < 4; ++r) {
      float vmax = acc[mt][0][r];
#pragma unroll
      for (int nt = 1; nt < 7; ++nt) vmax = fmaxf(vmax, acc[mt][nt][r]);
      float x7 = (l16 < 9) ? acc[mt][7][r] : -INFINITY;
      vmax = fmaxf(vmax, x7);
#pragma unroll
      for (int off = 1; off < 16; off <<= 1)
        vmax = fmaxf(vmax, __shfl_xor(vmax, off, 16));
      float es[8], sum = 0.f;
#pragma unroll
      for (int nt = 0; nt < 7; ++nt) { es[nt] = __expf(acc[mt][nt][r] - vmax); sum += es[nt]; }
      es[7] = (l16 < 9) ? __expf(acc[mt][7][r] - vmax) : 0.f;
      sum += es[7];
#pragma unroll
      for (int off = 1; off < 16; off <<= 1)
        sum += __shfl_xor(sum, off, 16);
      rinv[mt][r] = 1.f / sum;
      int arow = quad * 4 + r;
#pragma unroll
      for (int nt = 0; nt < 8; ++nt) {
        int a16 = (mt * 4 + (nt >> 1)) * 512 + ((((nt & 1) * 2 + hi) * 16 + arow) * 8) + lowl;
        pf[a16] = f2h(es[nt]);
      }
    }
  }
  __syncthreads();  // pf written

  // ---- O = P.V ----
  floatx4 o[2][4];
#pragma unroll
  for (int mt = 0; mt < 2; ++mt)
#pragma unroll
    for (int nd = 0; nd < 4; ++nd) o[mt][nd] = (floatx4){0.f, 0.f, 0.f, 0.f};
#pragma unroll
  for (int ks = 0; ks < 4; ++ks) {
    half8 a[2], b[4];
#pragma unroll
    for (int mt = 0; mt < 2; ++mt)
      a[mt] = *(const half8*)(&pf[(mt * 4 + ks) * 512 + t * 8]);
#pragma unroll
    for (int nd = 0; nd < 4; ++nd)
      b[nd] = *(const half8*)(&vt[(nd * 4 + ks) * 512 + t * 8]);
#pragma unroll
    for (int mt = 0; mt < 2; ++mt)
#pragma unroll
      for (int nd = 0; nd < 4; ++nd)
        o[mt][nd] = __builtin_amdgcn_mfma_f32_16x16x32_f16(a[mt], b[nd], o[mt][nd], 0, 0, 0);
  }

  // ---- epilogue: scale by 1/sum, store fp16 pixel-major (32B segments) ----
#pragma unroll
  for (int mt = 0; mt < 2; ++mt) {
#pragma unroll
    for (int r = 0; r < 4; ++r) {
      int i = mt * 16 + quad * 4 + r;
      if (i < 25) {
        int y = by * 5 + i / 5, x = bx * 5 + i % 5;
        float rs = rinv[mt][r];
        u16* ob = o16 + (hbase + y * 200 + x) * 256 + hoff;
#pragma unroll
        for (int nd = 0; nd < 4; ++nd)
          ob[nd * 16 + l16] = f2h(o[mt][nd][r] * rs);
      }
    }
  }
}

// ---------------- K3: transpose o16 [b][hw][256] f16 -> out [b][c][h][w] f32 ----------------
__global__ __launch_bounds__(256) void k_out(
    const u16* __restrict__ o16, float* __restrict__ out) {
  __shared__ __align__(16) u16 xs[64 * 264];
  int t = threadIdx.x;
  int bi = blockIdx.y;
  int hw0 = blockIdx.x * 64;
#pragma unroll
  for (int m = 0; m < 8; ++m) {
    int idx = m * 256 + t;
    int px = idx >> 5, sub = idx & 31;
    int sw = sub ^ ((px >> 2) & 7);
    *(uint4*)(&xs[px * 264 + sw * 8]) =
        *(const uint4*)(o16 + ((size_t)bi * HWSZ + hw0 + px) * 256 + sub * 8);
  }
  __syncthreads();
#pragma unroll
  for (int m = 0; m < 16; ++m) {
    int idx = m * 256 + t;
    int c = idx >> 4, g = idx & 15;
    int C8 = c >> 3, cl = c & 7;
    float4 vo;
    {
      int px = g * 4 + 0; int sw = C8 ^ ((px >> 2) & 7);
      vo.x = (float)(*(const f16*)&xs[px * 264 + sw * 8 + cl]);
    }
    {
      int px = g * 4 + 1; int sw = C8 ^ ((px >> 2) & 7);
      vo.y = (float)(*(const f16*)&xs[px * 264 + sw * 8 + cl]);
    }
    {
      int px = g * 4 + 2; int sw = C8 ^ ((px >> 2) & 7);
      vo.z = (float)(*(const f16*)&xs[px * 264 + sw * 8 + cl]);
    }
    {
      int px = g * 4 + 3; int sw = C8 ^ ((px >> 2) & 7);
      vo.w = (float)(*(const f16*)&xs[px * 264 + sw * 8 + cl]);
    }
    *(float4*)(out + ((size_t)(bi * 256 + c)) * HWSZ + hw0 + g * 4) = vo;
  }
}

extern "C" void kernel_launch(void* const* d_in, const int* in_sizes, int n_in,
                              void* d_out, int out_size, void* d_ws, size_t ws_size,
                              hipStream_t stream) {
  const float* noisy = (const float*)d_in[0];
  const float* aux   = (const float*)d_in[1];
  const float* Wmap  = (const float*)d_in[2];
  const float* bmap  = (const float*)d_in[3];
  const float* Wq    = (const float*)d_in[4];
  const float* Wk    = (const float*)d_in[5];
  const float* Wv    = (const float*)d_in[6];
  const float* relh  = (const float*)d_in[7];
  const float* relw  = (const float*)d_in[8];
  float* out = (float*)d_out;

  char* ws = (char*)d_ws;
  u16* naux  = (u16*)(ws);                   // 40,960,000; reused as o16 after k_qkv
  u16* q     = (u16*)(ws + 40960000);        // 40,960,000
  u16* k     = (u16*)(ws + 81920000);        // 40,960,000
  u16* v     = (u16*)(ws + 122880000);       // 40,960,000
  u16* wmapB = (u16*)(ws + 163840000);       // 262,144
  u16* wqB   = (u16*)(ws + 164102144);       // 131,072
  u16* wkB   = (u16*)(ws + 164233216);       // 131,072
  u16* wvB   = (u16*)(ws + 164364288);       // 131,072
  u16* relB  = (u16*)(ws + 164495360);       // 16,384 (end ~164.5 MB)
  u16* o16   = naux;                          // alias: naux fully consumed before k_attn

  k_tw<<<dim3(512, 5), 256, 0, stream>>>(Wmap, Wq, Wk, Wv, relh, relw,
                                         wmapB, wqB, wkB, wvB, relB);
  k_naux<<<dim3(1250, 2), 256, 0, stream>>>(noisy, aux, wmapB, bmap, naux);
  k_qkv<<<dim3(1250, 2), 256, 0, stream>>>(naux, noisy, wqB, wkB, wvB, q, k, v);
  k_attn<<<dim3(1600, 4, 2), 64, 0, stream>>>(q, k, v, relB, o16);
  k_out<<<dim3(625, 2), 256, 0, stream>>>(o16, out);
}